// Round 8
// baseline (1127.520 us; speedup 1.0000x reference)
//
#include <hip/hip_runtime.h>

// DeepRLSNet: batched RLS. B=64, N=T=2000, TAPS=64.
//
// R20 = R19 (902us harness best) + BIT-EXACT halving of LDS slice traffic
// via cross-lane DPP sharing:
//   Per round each lane previously read 4 slice-vectors (16 ds_read_b128);
//   64 such wave-instructions/CU cluster post-barrier => ~770cy of serial
//   DS-pipe drain (~37% of the round) — the dominant unexplained stall
//   (consistent with R13/R14 DS-traffic scaling).
//   Lanes tid and tid+8 (same 16-lane DPP row, same column-quarter q) need
//   the SAME slices. Parity p=(tid>>3)&1: even lanes read {Qx,xQ} slices,
//   odd lanes read {u,v}; one row_ror:8 DPP pass (involution: swaps 8-lane
//   halves of each 16-row) hands each lane its partner's pair. The bits are
//   identical to a direct read -> bit-exact, zero algorithm change.
//   Cost: 32 v_mov_dpp + 32 cndmask per lane (~+128cy issue). Benefit:
//   DS drain halved (8 ds_read_b128/lane instead of 16).
// Everything else verbatim R19. Canary: absmax must be exactly 0.015625.

#define B_ 64
#define N_ 2000
#define TAPS_ 64
#define STEPS_ 2000
#define VST_ 72   // padded LDS vector stride; banks r+8q -> 2-way max (free)

typedef float f2 __attribute__((ext_vector_type(2)));

__device__ __forceinline__ f2 pk2(float v) { f2 r; r.x = v; r.y = v; return r; }

__device__ __forceinline__ void lds_barrier() {
    // LDS-only fence + barrier: global (vmcnt) prefetch stays in flight.
    asm volatile("s_waitcnt lgkmcnt(0)\n\ts_barrier" ::: "memory");
}

__device__ __forceinline__ float clipl(float v) {
    return fminf(fmaxf(v, 1e-4f), 0.9999f);
}

// sum over the 4 q-lanes of a quad via DPP quad_perm (identical to R19).
__device__ __forceinline__ float quad_reduce(float v) {
    int t1 = __builtin_amdgcn_update_dpp(__float_as_int(v), __float_as_int(v),
                                         0xB1, 0xF, 0xF, false);   // xor 1
    v += __int_as_float(t1);
    int t2 = __builtin_amdgcn_update_dpp(__float_as_int(v), __float_as_int(v),
                                         0x4E, 0xF, 0xF, false);   // xor 2
    v += __int_as_float(t2);
    return v;   // bitwise-identical in all 4 lanes of the quad
}

// row_ror:8 (ctrl 0x128): swap 8-lane halves within each 16-lane row.
// Involution -> one pass exchanges data both ways between lane L and L^8
// (same 16-row). Pure data movement: bits identical to a direct read.
__device__ __forceinline__ float dpp_ror8(float v) {
    int t = __builtin_amdgcn_update_dpp(__float_as_int(v), __float_as_int(v),
                                        0x128, 0xF, 0xF, false);
    return __int_as_float(t);
}
__device__ __forceinline__ f2 dpp_ror8_f2(f2 v) {
    f2 r; r.x = dpp_ror8(v.x); r.y = dpp_ror8(v.y); return r;
}

// 1/v via v_rcp_f32 + one Newton step (~0.5 ulp). Identical to R19.
__device__ __forceinline__ float rcp_nr(float v) {
    float r = __builtin_amdgcn_rcpf(v);
    float e = fmaf(-v, r, 1.0f);
    return fmaf(r, e, r);
}

__global__ __launch_bounds__(256, 1) void rls_kernel(
    const float* __restrict__ x_seq,   // [B, N, TAPS]
    const float* __restrict__ d_seq,   // [B, N]
    const float* __restrict__ lambdas, // [T]
    float* __restrict__ y_out,         // [B, N]
    float* __restrict__ w_out)         // [B, TAPS]
{
    const int b   = blockIdx.x;
    const int tid = threadIdx.x;
    const int r   = tid >> 2;    // row 0..63
    const int q   = tid & 3;     // quarter 0..3
    const int qb  = q << 4;
    const int p   = (tid >> 3) & 1;   // DPP-pair parity (quad-index bit 1)

    // [parity][vec][VST_], vec: 0=Qx 1=xQ 2=u 3=v  (R12/R19 layout)
    __shared__ __align__(16) float  bufs[2][4][VST_];
    __shared__ __align__(16) float  d_lds[STEPS_];
    __shared__ __align__(16) float2 lam2[STEPS_];   // {clip(lam), rcp_nr(clip(lam))}

    const float* xb = x_seq + (size_t)b * N_ * TAPS_;
    const float* db = d_seq + (size_t)b * N_;

    for (int idx = tid; idx < STEPS_; idx += 256) {
        d_lds[idx] = db[idx];
        const float lc = clipl(lambdas[idx]);
        lam2[idx] = make_float2(lc, rcp_nr(lc));
    }

    f2 Q[8], QT[8], w[8];
    #pragma unroll
    for (int j = 0; j < 8; ++j) {
        Q[j].x = (qb + 2*j     == r) ? 1.0f : 0.0f;
        Q[j].y = (qb + 2*j + 1 == r) ? 1.0f : 0.0f;
        QT[j] = Q[j];
        w[j]  = pk2(0.0f);
    }
    float sig = 1.0f;   // P = sig * Q

    auto unpack4 = [](f2* dst, float4 v) {
        dst[0].x = v.x; dst[0].y = v.y; dst[1].x = v.z; dst[1].y = v.w;
    };

    auto loadpair = [&](f2 (&dA)[8], f2 (&dB)[8], int row) {
        const float4* v0 = (const float4*)(xb + (size_t)row * TAPS_ + qb);
        const float4* v1 = (const float4*)(xb + (size_t)(row + 1) * TAPS_ + qb);
        #pragma unroll
        for (int j4 = 0; j4 < 4; ++j4) {
            unpack4(&dA[2*j4], v0[j4]);
            unpack4(&dB[2*j4], v1[j4]);
        }
    };

    // 4 rotating row-pairs (R15 rotation). Round k: x=pair k&3, xn=(k+1)&3,
    // prefetch rows t+6,t+7 into pair (k+3)&3.
    f2 P0a[8], P0b[8], P1a[8], P1b[8], P2a[8], P2b[8], P3a[8], P3b[8];
    loadpair(P0a, P0b, 0);
    loadpair(P1a, P1b, 2);
    loadpair(P2a, P2b, 4);

    // loop-carried reduced row values (produced by prologue / fused phase).
    float qxrS, xqrS, urS, vrS, wy0S, wy1S;

    // ---- prologue: round 0's exchange data, R19 pre-phase bit-for-bit ----
    {
        f2 qx2 = pk2(0.f), xq2 = pk2(0.f), u2 = pk2(0.f), v2 = pk2(0.f);
        #pragma unroll
        for (int j = 0; j < 8; ++j) {
            qx2 = __builtin_elementwise_fma(Q[j],  P0a[j], qx2);
            xq2 = __builtin_elementwise_fma(QT[j], P0a[j], xq2);
            u2  = __builtin_elementwise_fma(Q[j],  P0b[j], u2);
            v2  = __builtin_elementwise_fma(QT[j], P0b[j], v2);
        }
        qxrS = quad_reduce(qx2.x + qx2.y);
        xqrS = quad_reduce(xq2.x + xq2.y);
        urS  = quad_reduce(u2.x + u2.y);
        vrS  = quad_reduce(v2.x + v2.y);
        bufs[0][q][r] = (q == 0) ? qxrS : (q == 1) ? xqrS : (q == 2) ? urS : vrS;

        f2 wy02 = pk2(0.f), wy12 = pk2(0.f);
        #pragma unroll
        for (int j = 0; j < 8; ++j) {
            wy02 = __builtin_elementwise_fma(w[j], P0a[j], wy02);
            wy12 = __builtin_elementwise_fma(w[j], P0b[j], wy12);
        }
        wy0S = quad_reduce(wy02.x + wy02.y);
        wy1S = quad_reduce(wy12.x + wy12.y);
    }

    auto round = [&](int t, f2 (&x0)[8], f2 (&x1)[8],
                     f2 (&xn0)[8], f2 (&xn1)[8],
                     f2 (&xf0)[8], f2 (&xf1)[8],
                     int par, bool pf, bool fuse)
    {
        lds_barrier();   // exchange data (written last round) visible

        // ---- parity slice reads: even lanes read {Qx,xQ}, odd read {u,v}
        //      (8 ds_read_b128/lane — HALF of R19's 16) ----
        f2 nA[8], nB[8];
        {
            const float4* pA = (const float4*)(&bufs[par][p ? 2 : 0][qb]);
            const float4* pB = (const float4*)(&bufs[par][p ? 3 : 1][qb]);
            #pragma unroll
            for (int j4 = 0; j4 < 4; ++j4) {
                unpack4(&nA[2*j4], pA[j4]);
                unpack4(&nB[2*j4], pB[j4]);
            }
        }
        // lam pair fused to one b128 (t even -> 16B aligned; same bits).
        const float4 lf = *(const float4*)&lam2[t];   // {l0.x,l0.y,l1.x,l1.y}
        const float2 dd = *(const float2*)&d_lds[t];

        // ---- deep prefetch (global pipe; rides across barriers) ----
        if (pf) loadpair(xf0, xf1, t + 6);

        // ---- DPP half-row swap: partner lane (same q, opposite parity)
        //      supplies the other two slices. Bits identical to a read. ----
        f2 dA[8], dB[8];
        #pragma unroll
        for (int j = 0; j < 8; ++j) {
            dA[j] = dpp_ror8_f2(nA[j]);
            dB[j] = dpp_ror8_f2(nB[j]);
        }
        f2 Qxq[8], xQq[8], uq[8], vq[8];
        #pragma unroll
        for (int j = 0; j < 8; ++j) {
            Qxq[j] = p ? dA[j] : nA[j];
            xQq[j] = p ? dB[j] : nB[j];
            uq[j]  = p ? nA[j] : dA[j];
            vq[j]  = p ? nB[j] : dB[j];
        }

        // ---- pd chain first, then den0->rcp->s0 early (overlaps a/bb/c2) ----
        f2 pd2 = pk2(0.f);
        #pragma unroll
        for (int j = 0; j < 8; ++j)
            pd2 = __builtin_elementwise_fma(x0[j], Qxq[j], pd2);
        const float pd0  = quad_reduce(pd2.x + pd2.y);
        const float den0 = fmaf(sig, pd0, lf.x);
        const float s0   = sig * rcp_nr(den0);

        // ---- a, bb chains, then c2 ----
        f2 a2 = pk2(0.f), bb2 = pk2(0.f);
        #pragma unroll
        for (int j = 0; j < 8; ++j) {
            a2  = __builtin_elementwise_fma(x1[j], xQq[j], a2);
            bb2 = __builtin_elementwise_fma(x1[j], Qxq[j], bb2);
        }
        const float a  = quad_reduce(a2.x + a2.y);
        const float bb = quad_reduce(bb2.x + bb2.y);

        f2 c22 = pk2(0.f);
        #pragma unroll
        for (int j = 0; j < 8; ++j)
            c22 = __builtin_elementwise_fma(x1[j], uq[j], c22);
        const float c2 = quad_reduce(c22.x + c22.y);

        // ---- scalars (R19 op order for everything downstream of s0) ----
        const float err0 = dd.x - wy0S;
        const float es0  = s0 * err0;
        const float sa   = s0 * a;
        const float sb   = s0 * bb;

        const float sig1 = sig * lf.y;
        const float pd1  = fmaf(-sa, bb, c2);
        const float den1 = fmaf(sig1, pd1, lf.z);
        const float s1   = sig1 * rcp_nr(den1);
        const float y1   = fmaf(es0, bb, wy1S);
        const float err1 = dd.y - y1;
        const float es1  = s1 * err1;
        sig = sig1 * lf.w;

        if (tid == 0)
            *(float2*)(y_out + (size_t)b * N_ + t) = make_float2(wy0S, y1);

        // ---- pass1: dual rank-1 updates fused with next-dots (R19 bits) ----
        const float qx1r = fmaf(-sa, qxrS, urS);
        const float xq1r = fmaf(-sb, xqrS, vrS);
        const f2 nsa   = pk2(-sa);
        const f2 nsb   = pk2(-sb);
        const f2 s0v   = pk2(s0);
        const f2 s1v   = pk2(s1);
        const f2 es0v  = pk2(es0);
        const f2 es1v  = pk2(es1);
        const f2 ntr0  = pk2(-(s0 * qxrS));
        const f2 ntr1  = pk2(-(s1 * qx1r));
        const f2 nxqr  = pk2(-xqrS);
        const f2 nxq1r = pk2(-xq1r);

        f2 nqx = pk2(0.f), nxq = pk2(0.f), nu = pk2(0.f), nv = pk2(0.f);
        f2 nw0 = pk2(0.f), nw1 = pk2(0.f);

        #pragma unroll
        for (int j = 0; j < 8; ++j) {
            const f2 Qx1 = __builtin_elementwise_fma(nsa, Qxq[j], uq[j]);
            const f2 xQ1 = __builtin_elementwise_fma(nsb, xQq[j], vq[j]);
            const f2 tq0 = s0v * Qxq[j];
            const f2 tq1 = s1v * Qx1;
            // w: two honest rank-1 adds
            w[j] = __builtin_elementwise_fma(Qxq[j], es0v, w[j]);
            w[j] = __builtin_elementwise_fma(Qx1,    es1v, w[j]);
            // Q row r: subtract both outer-product terms
            Q[j] = __builtin_elementwise_fma(ntr0, xQq[j], Q[j]);
            Q[j] = __builtin_elementwise_fma(ntr1, xQ1,    Q[j]);
            // QT row r (= Q column r): transposed products, identical bits
            QT[j] = __builtin_elementwise_fma(tq0, nxqr,  QT[j]);
            QT[j] = __builtin_elementwise_fma(tq1, nxq1r, QT[j]);
            // fused next-round pre-dots on the freshly updated registers
            if (fuse) {
                nqx = __builtin_elementwise_fma(Q[j],  xn0[j], nqx);
                nxq = __builtin_elementwise_fma(QT[j], xn0[j], nxq);
                nu  = __builtin_elementwise_fma(Q[j],  xn1[j], nu);
                nv  = __builtin_elementwise_fma(QT[j], xn1[j], nv);
                nw0 = __builtin_elementwise_fma(w[j],  xn0[j], nw0);
                nw1 = __builtin_elementwise_fma(w[j],  xn1[j], nw1);
            }
        }

        if (fuse) {
            qxrS = quad_reduce(nqx.x + nqx.y);
            xqrS = quad_reduce(nxq.x + nxq.y);
            urS  = quad_reduce(nu.x + nu.y);
            vrS  = quad_reduce(nv.x + nv.y);
            bufs[par ^ 1][q][r] =
                (q == 0) ? qxrS : (q == 1) ? xqrS : (q == 2) ? urS : vrS;
            wy0S = quad_reduce(nw0.x + nw0.y);
            wy1S = quad_reduce(nw1.x + nw1.y);
        }
    };

    // main loop: rounds k=0..995 (t=0..1990), 4-round unroll for pair rotation.
    for (int t = 0; t < 1992; t += 8) {
        round(t + 0, P0a, P0b, P1a, P1b, P3a, P3b, 0, true, true);
        round(t + 2, P1a, P1b, P2a, P2b, P0a, P0b, 1, true, true);
        round(t + 4, P2a, P2b, P3a, P3b, P1a, P1b, 0, true, true);
        round(t + 6, P3a, P3b, P0a, P0b, P2a, P2b, 1, true, true);
    }
    // tail (same flags as R19)
    round(1992, P0a, P0b, P1a, P1b, P3a, P3b, 0, true,  true);
    round(1994, P1a, P1b, P2a, P2b, P0a, P0b, 1, false, true);
    round(1996, P2a, P2b, P3a, P3b, P1a, P1b, 0, false, true);
    round(1998, P3a, P3b, P0a, P0b, P2a, P2b, 1, false, false);

    // ---- final weights: row-group 0 holds a full replica across q ----
    if (r == 0) {
        float4* wo = (float4*)(w_out + (size_t)b * TAPS_ + qb);
        #pragma unroll
        for (int j4 = 0; j4 < 4; ++j4)
            wo[j4] = make_float4(w[2*j4].x, w[2*j4].y, w[2*j4+1].x, w[2*j4+1].y);
    }
}

extern "C" void kernel_launch(void* const* d_in, const int* in_sizes, int n_in,
                              void* d_out, int out_size, void* d_ws, size_t ws_size,
                              hipStream_t stream) {
    const float* x_seq   = (const float*)d_in[0];
    const float* d_seq   = (const float*)d_in[1];
    const float* lambdas = (const float*)d_in[2];

    float* y_out = (float*)d_out;                      // B*N floats
    float* w_out = (float*)d_out + (size_t)B_ * N_;    // B*TAPS floats

    rls_kernel<<<B_, 256, 0, stream>>>(x_seq, d_seq, lambdas, y_out, w_out);
}

// Round 10
// 900.402 us; speedup vs baseline: 1.2522x; 1.2522x over previous
//
#include <hip/hip_runtime.h>

// DeepRLSNet: batched RLS. B=64, N=T=2000, TAPS=64.
//
// R22 = R19 (best: 902us harness / 866us rocprof) + R21's fused-DPP reduce,
// FIXED: v_add_f32_dpp requires 2 wait states between a VALU write and a DPP
// read of the same VGPR (software-managed hazard; the compiler inserts these
// for builtins but cannot see inline asm -> R21's NaN). Explicit s_nop 1
// before each DPP stage. Dependent path per reduce: ~12cy vs ~20cy for the
// builtin mov_dpp+add form when hazard slots can't be filled — matters at
// the 3 scalar gates (pd->s0, bb->sa/sb, c2->s1) and the 6 back-to-back
// end-of-round reduces. dpp(v)+v vs v+dpp(v): commutative, same rounding ->
// bit-identical. Everything else verbatim R19.
// Canary: absmax must be exactly 0.015625.

#define B_ 64
#define N_ 2000
#define TAPS_ 64
#define STEPS_ 2000
#define VST_ 72   // padded LDS vector stride; banks r+8q -> 2-way max (free)

typedef float f2 __attribute__((ext_vector_type(2)));

__device__ __forceinline__ f2 pk2(float v) { f2 r; r.x = v; r.y = v; return r; }

__device__ __forceinline__ void lds_barrier() {
    // LDS-only fence + barrier: global (vmcnt) prefetch stays in flight.
    asm volatile("s_waitcnt lgkmcnt(0)\n\ts_barrier" ::: "memory");
}

__device__ __forceinline__ float clipl(float v) {
    return fminf(fmaxf(v, 1e-4f), 0.9999f);
}

// sum over the 4 q-lanes of a quad, FUSED DPP adds with explicit hazard
// guards (bit-identical to the R12..R19 builtin version: same adds, same
// rounding; addition commutes).
//   stage1: t = quad_perm[1,0,3,2](v) + v   (xor 1)
//   stage2: r = quad_perm[2,3,0,1](t) + t   (xor 2)
// s_nop 1 = 2 wait states, required before each DPP read of a VALU-written
// VGPR (gfx9-lineage DPP hazard; R21 omitted these -> NaN).
__device__ __forceinline__ float quad_reduce(float v) {
    float r;
    asm("s_nop 1\n\t"
        "v_add_f32_dpp %0, %1, %1 quad_perm:[1,0,3,2] row_mask:0xf bank_mask:0xf\n\t"
        "s_nop 1\n\t"
        "v_add_f32_dpp %0, %0, %0 quad_perm:[2,3,0,1] row_mask:0xf bank_mask:0xf"
        : "=&v"(r) : "v"(v));
    return r;   // bitwise-identical in all 4 lanes of the quad
}

// 1/v via v_rcp_f32 + one Newton step (~0.5 ulp). Identical to R19.
__device__ __forceinline__ float rcp_nr(float v) {
    float r = __builtin_amdgcn_rcpf(v);
    float e = fmaf(-v, r, 1.0f);
    return fmaf(r, e, r);
}

__global__ __launch_bounds__(256, 1) void rls_kernel(
    const float* __restrict__ x_seq,   // [B, N, TAPS]
    const float* __restrict__ d_seq,   // [B, N]
    const float* __restrict__ lambdas, // [T]
    float* __restrict__ y_out,         // [B, N]
    float* __restrict__ w_out)         // [B, TAPS]
{
    const int b   = blockIdx.x;
    const int tid = threadIdx.x;
    const int r   = tid >> 2;    // row 0..63
    const int q   = tid & 3;     // quarter 0..3
    const int qb  = q << 4;

    // [parity][vec][VST_], vec: 0=Qx 1=xQ 2=u 3=v  (R12/R19 layout)
    __shared__ __align__(16) float  bufs[2][4][VST_];
    __shared__ __align__(16) float  d_lds[STEPS_];
    __shared__ __align__(16) float2 lam2[STEPS_];   // {clip(lam), rcp_nr(clip(lam))}

    const float* xb = x_seq + (size_t)b * N_ * TAPS_;
    const float* db = d_seq + (size_t)b * N_;

    for (int idx = tid; idx < STEPS_; idx += 256) {
        d_lds[idx] = db[idx];
        const float lc = clipl(lambdas[idx]);
        lam2[idx] = make_float2(lc, rcp_nr(lc));
    }

    f2 Q[8], QT[8], w[8];
    #pragma unroll
    for (int j = 0; j < 8; ++j) {
        Q[j].x = (qb + 2*j     == r) ? 1.0f : 0.0f;
        Q[j].y = (qb + 2*j + 1 == r) ? 1.0f : 0.0f;
        QT[j] = Q[j];
        w[j]  = pk2(0.0f);
    }
    float sig = 1.0f;   // P = sig * Q

    auto unpack4 = [](f2* dst, float4 v) {
        dst[0].x = v.x; dst[0].y = v.y; dst[1].x = v.z; dst[1].y = v.w;
    };

    auto loadpair = [&](f2 (&dA)[8], f2 (&dB)[8], int row) {
        const float4* v0 = (const float4*)(xb + (size_t)row * TAPS_ + qb);
        const float4* v1 = (const float4*)(xb + (size_t)(row + 1) * TAPS_ + qb);
        #pragma unroll
        for (int j4 = 0; j4 < 4; ++j4) {
            unpack4(&dA[2*j4], v0[j4]);
            unpack4(&dB[2*j4], v1[j4]);
        }
    };

    // 4 rotating row-pairs (R15 rotation). Round k: x=pair k&3, xn=(k+1)&3,
    // prefetch rows t+6,t+7 into pair (k+3)&3.
    f2 P0a[8], P0b[8], P1a[8], P1b[8], P2a[8], P2b[8], P3a[8], P3b[8];
    loadpair(P0a, P0b, 0);
    loadpair(P1a, P1b, 2);
    loadpair(P2a, P2b, 4);

    // loop-carried reduced row values (produced by prologue / fused phase).
    float qxrS, xqrS, urS, vrS, wy0S, wy1S;

    // ---- prologue: round 0's exchange data, R19 pre-phase bit-for-bit ----
    {
        f2 qx2 = pk2(0.f), xq2 = pk2(0.f), u2 = pk2(0.f), v2 = pk2(0.f);
        #pragma unroll
        for (int j = 0; j < 8; ++j) {
            qx2 = __builtin_elementwise_fma(Q[j],  P0a[j], qx2);
            xq2 = __builtin_elementwise_fma(QT[j], P0a[j], xq2);
            u2  = __builtin_elementwise_fma(Q[j],  P0b[j], u2);
            v2  = __builtin_elementwise_fma(QT[j], P0b[j], v2);
        }
        qxrS = quad_reduce(qx2.x + qx2.y);
        xqrS = quad_reduce(xq2.x + xq2.y);
        urS  = quad_reduce(u2.x + u2.y);
        vrS  = quad_reduce(v2.x + v2.y);
        bufs[0][q][r] = (q == 0) ? qxrS : (q == 1) ? xqrS : (q == 2) ? urS : vrS;

        f2 wy02 = pk2(0.f), wy12 = pk2(0.f);
        #pragma unroll
        for (int j = 0; j < 8; ++j) {
            wy02 = __builtin_elementwise_fma(w[j], P0a[j], wy02);
            wy12 = __builtin_elementwise_fma(w[j], P0b[j], wy12);
        }
        wy0S = quad_reduce(wy02.x + wy02.y);
        wy1S = quad_reduce(wy12.x + wy12.y);
    }

    auto round = [&](int t, f2 (&x0)[8], f2 (&x1)[8],
                     f2 (&xn0)[8], f2 (&xn1)[8],
                     f2 (&xf0)[8], f2 (&xf1)[8],
                     int par, bool pf, bool fuse)
    {
        lds_barrier();   // exchange data (written last round) visible

        // ---- issue ALL slice ds_reads up-front: group-1 (Qxq,xQq) first
        //      so they arrive first, then group-2 (uq,vq) ----
        f2 Qxq[8], xQq[8], uq[8], vq[8];
        {
            const float4* p0 = (const float4*)(&bufs[par][0][qb]);
            const float4* p1 = (const float4*)(&bufs[par][1][qb]);
            #pragma unroll
            for (int j4 = 0; j4 < 4; ++j4) {
                unpack4(&Qxq[2*j4], p0[j4]);
                unpack4(&xQq[2*j4], p1[j4]);
            }
            const float4* p2 = (const float4*)(&bufs[par][2][qb]);
            const float4* p3 = (const float4*)(&bufs[par][3][qb]);
            #pragma unroll
            for (int j4 = 0; j4 < 4; ++j4) {
                unpack4(&uq[2*j4], p2[j4]);
                unpack4(&vq[2*j4], p3[j4]);
            }
        }
        // lam pair fused to one b128 (t even -> 16B aligned; same bits).
        const float4 lf = *(const float4*)&lam2[t];   // {l0.x,l0.y,l1.x,l1.y}
        const float2 dd = *(const float2*)&d_lds[t];

        // ---- deep prefetch (global pipe; rides across barriers) ----
        if (pf) loadpair(xf0, xf1, t + 6);

        // ---- pd chain first, then den0->rcp->s0 early (overlaps a/bb/c2) ----
        f2 pd2 = pk2(0.f);
        #pragma unroll
        for (int j = 0; j < 8; ++j)
            pd2 = __builtin_elementwise_fma(x0[j], Qxq[j], pd2);
        const float pd0  = quad_reduce(pd2.x + pd2.y);
        const float den0 = fmaf(sig, pd0, lf.x);
        const float s0   = sig * rcp_nr(den0);

        // ---- a, bb chains (group-1 data), then c2 (group-2 data) ----
        f2 a2 = pk2(0.f), bb2 = pk2(0.f);
        #pragma unroll
        for (int j = 0; j < 8; ++j) {
            a2  = __builtin_elementwise_fma(x1[j], xQq[j], a2);
            bb2 = __builtin_elementwise_fma(x1[j], Qxq[j], bb2);
        }
        const float a  = quad_reduce(a2.x + a2.y);
        const float bb = quad_reduce(bb2.x + bb2.y);

        f2 c22 = pk2(0.f);
        #pragma unroll
        for (int j = 0; j < 8; ++j)
            c22 = __builtin_elementwise_fma(x1[j], uq[j], c22);
        const float c2 = quad_reduce(c22.x + c22.y);

        // ---- scalars (R19 op order for everything downstream of s0) ----
        const float err0 = dd.x - wy0S;
        const float es0  = s0 * err0;
        const float sa   = s0 * a;
        const float sb   = s0 * bb;

        const float sig1 = sig * lf.y;
        const float pd1  = fmaf(-sa, bb, c2);
        const float den1 = fmaf(sig1, pd1, lf.z);
        const float s1   = sig1 * rcp_nr(den1);
        const float y1   = fmaf(es0, bb, wy1S);
        const float err1 = dd.y - y1;
        const float es1  = s1 * err1;
        sig = sig1 * lf.w;

        if (tid == 0)
            *(float2*)(y_out + (size_t)b * N_ + t) = make_float2(wy0S, y1);

        // ---- pass1: dual rank-1 updates fused with next-dots (R19 bits) ----
        const float qx1r = fmaf(-sa, qxrS, urS);
        const float xq1r = fmaf(-sb, xqrS, vrS);
        const f2 nsa   = pk2(-sa);
        const f2 nsb   = pk2(-sb);
        const f2 s0v   = pk2(s0);
        const f2 s1v   = pk2(s1);
        const f2 es0v  = pk2(es0);
        const f2 es1v  = pk2(es1);
        const f2 ntr0  = pk2(-(s0 * qxrS));
        const f2 ntr1  = pk2(-(s1 * qx1r));
        const f2 nxqr  = pk2(-xqrS);
        const f2 nxq1r = pk2(-xq1r);

        f2 nqx = pk2(0.f), nxq = pk2(0.f), nu = pk2(0.f), nv = pk2(0.f);
        f2 nw0 = pk2(0.f), nw1 = pk2(0.f);

        #pragma unroll
        for (int j = 0; j < 8; ++j) {
            const f2 Qx1 = __builtin_elementwise_fma(nsa, Qxq[j], uq[j]);
            const f2 xQ1 = __builtin_elementwise_fma(nsb, xQq[j], vq[j]);
            const f2 tq0 = s0v * Qxq[j];
            const f2 tq1 = s1v * Qx1;
            // w: two honest rank-1 adds
            w[j] = __builtin_elementwise_fma(Qxq[j], es0v, w[j]);
            w[j] = __builtin_elementwise_fma(Qx1,    es1v, w[j]);
            // Q row r: subtract both outer-product terms
            Q[j] = __builtin_elementwise_fma(ntr0, xQq[j], Q[j]);
            Q[j] = __builtin_elementwise_fma(ntr1, xQ1,    Q[j]);
            // QT row r (= Q column r): transposed products, identical bits
            QT[j] = __builtin_elementwise_fma(tq0, nxqr,  QT[j]);
            QT[j] = __builtin_elementwise_fma(tq1, nxq1r, QT[j]);
            // fused next-round pre-dots on the freshly updated registers
            if (fuse) {
                nqx = __builtin_elementwise_fma(Q[j],  xn0[j], nqx);
                nxq = __builtin_elementwise_fma(QT[j], xn0[j], nxq);
                nu  = __builtin_elementwise_fma(Q[j],  xn1[j], nu);
                nv  = __builtin_elementwise_fma(QT[j], xn1[j], nv);
                nw0 = __builtin_elementwise_fma(w[j],  xn0[j], nw0);
                nw1 = __builtin_elementwise_fma(w[j],  xn1[j], nw1);
            }
        }

        if (fuse) {
            qxrS = quad_reduce(nqx.x + nqx.y);
            xqrS = quad_reduce(nxq.x + nxq.y);
            urS  = quad_reduce(nu.x + nu.y);
            vrS  = quad_reduce(nv.x + nv.y);
            bufs[par ^ 1][q][r] =
                (q == 0) ? qxrS : (q == 1) ? xqrS : (q == 2) ? urS : vrS;
            wy0S = quad_reduce(nw0.x + nw0.y);
            wy1S = quad_reduce(nw1.x + nw1.y);
        }
    };

    // main loop: rounds k=0..995 (t=0..1990), 4-round unroll for pair rotation.
    for (int t = 0; t < 1992; t += 8) {
        round(t + 0, P0a, P0b, P1a, P1b, P3a, P3b, 0, true, true);
        round(t + 2, P1a, P1b, P2a, P2b, P0a, P0b, 1, true, true);
        round(t + 4, P2a, P2b, P3a, P3b, P1a, P1b, 0, true, true);
        round(t + 6, P3a, P3b, P0a, P0b, P2a, P2b, 1, true, true);
    }
    // tail (same flags as R19)
    round(1992, P0a, P0b, P1a, P1b, P3a, P3b, 0, true,  true);
    round(1994, P1a, P1b, P2a, P2b, P0a, P0b, 1, false, true);
    round(1996, P2a, P2b, P3a, P3b, P1a, P1b, 0, false, true);
    round(1998, P3a, P3b, P0a, P0b, P2a, P2b, 1, false, false);

    // ---- final weights: row-group 0 holds a full replica across q ----
    if (r == 0) {
        float4* wo = (float4*)(w_out + (size_t)b * TAPS_ + qb);
        #pragma unroll
        for (int j4 = 0; j4 < 4; ++j4)
            wo[j4] = make_float4(w[2*j4].x, w[2*j4].y, w[2*j4+1].x, w[2*j4+1].y);
    }
}

extern "C" void kernel_launch(void* const* d_in, const int* in_sizes, int n_in,
                              void* d_out, int out_size, void* d_ws, size_t ws_size,
                              hipStream_t stream) {
    const float* x_seq   = (const float*)d_in[0];
    const float* d_seq   = (const float*)d_in[1];
    const float* lambdas = (const float*)d_in[2];

    float* y_out = (float*)d_out;                      // B*N floats
    float* w_out = (float*)d_out + (size_t)B_ * N_;    // B*TAPS floats

    rls_kernel<<<B_, 256, 0, stream>>>(x_seq, d_seq, lambdas, y_out, w_out);
}